// Round 2
// baseline (666.159 us; speedup 1.0000x reference)
//
#include <hip/hip_runtime.h>
#include <stdint.h>

typedef int v4i __attribute__((ext_vector_type(4)));

constexpr int K_DIM = 4096;
constexpr int N_DIM = 4096;
constexpr int TM = 128;
constexpr int TN = 128;
constexpr int TK = 64;               // one i8 MFMA K-step per tile
constexpr int KSTEPS = K_DIM / TK;   // 64

// pack low bytes of 4 int32 (each holding one int8 value) into one dword,
// byte 0 = first value (little-endian k order for the MFMA A/B fragment)
__device__ __forceinline__ int pack4(int a, int b, int c, int d) {
    unsigned r = (unsigned(a) & 0xFFu)
               | ((unsigned(b) & 0xFFu) << 8)
               | ((unsigned(c) & 0xFFu) << 16)
               | (unsigned(d) << 24);
    return (int)r;
}

// C[m][n] = alpha * sum_k X[m][k]*W[n][k] + bias[n]
// Inputs are int32 buffers holding int8 values (harness widens integers).
// Block tile 128x128, 4 waves (2x2 of 64x64), 4x4 of 16x16x64 i8 MFMAs/wave.
__global__ __launch_bounds__(256, 2) void w8a8_gemm(
    const int*   __restrict__ X,      // [M][K] int32 (values in [-127,127])
    const int*   __restrict__ Wt,     // [N][K] int32 (weight, row-major = B^T)
    const float* __restrict__ bias,   // [N]
    const float* __restrict__ alphap, // scalar
    float* __restrict__ Y)            // [M][N] fp32
{
    // packed int8 tiles, 8 KB each. Row = 64 int8 = 16 dwords = 4 chunks of 16B.
    // Swizzle: 16B chunk c of row r stored at slot (c ^ ((r>>1)&3)).
    __shared__ __align__(16) int8_t As[TM * TK];
    __shared__ __align__(16) int8_t Bs[TN * TK];

    const int tid  = threadIdx.x;
    const int lane = tid & 63;
    const int wave = tid >> 6;

    const int m0 = blockIdx.x * TM;
    const int n0 = blockIdx.y * TN;

    // ---- staging geometry ----
    // Round r in [0,4): thread loads 8 int32 from local row (r*32 + tid/8),
    // k = (tid&7)*8 .. +7 (two dwordx4, coalesced across lanes).
    const int srow = tid >> 3;        // 0..31 (+ r*32)
    const int sk   = (tid & 7) * 8;   // 0..56

    const int* Ag = X  + (size_t)(m0 + srow) * K_DIM + sk;
    const int* Bg = Wt + (size_t)(n0 + srow) * K_DIM + sk;

    // LDS write byte offsets (packed): thread's packed dwords p = r*512 + tid*2 (+1).
    // row = p>>4, dw = p&15 (even). Swizzled dword = row*16 + ((dw>>2)^f(row))*4 + (dw&3).
    int wr_off[4];
#pragma unroll
    for (int r = 0; r < 4; ++r) {
        const int row = r * 32 + (tid >> 3);
        const int dw  = (tid & 7) * 2;
        const int sw  = row * 16 + (((dw >> 2) ^ ((row >> 1) & 3)) << 2) + (dw & 3);
        wr_off[r] = sw * 4;
    }

    // ---- compute geometry ----
    const int wm   = (wave & 1) << 6;
    const int wn   = (wave >> 1) << 6;
    const int lrow = lane & 15;       // m (A) / n (B) within 16-tile
    const int quad = lane >> 4;       // k-chunk selector

    int a_off[4], b_off[4];
#pragma unroll
    for (int i = 0; i < 4; ++i) {
        const int ra = wm + i * 16 + lrow;
        a_off[i] = ra * 64 + ((quad ^ ((ra >> 1) & 3)) << 4);
        const int rb = wn + i * 16 + lrow;
        b_off[i] = rb * 64 + ((quad ^ ((rb >> 1) & 3)) << 4);
    }

    v4i acc[4][4] = {};
    v4i av[8], bv[8];   // current tile staged in registers (int32 values)

    // prefetch tile 0
#pragma unroll
    for (int r = 0; r < 4; ++r) {
        const int* pa = Ag + (size_t)r * 32 * K_DIM;
        const int* pb = Bg + (size_t)r * 32 * K_DIM;
        av[2 * r]     = *(const v4i*)(pa);
        av[2 * r + 1] = *(const v4i*)(pa + 4);
        bv[2 * r]     = *(const v4i*)(pb);
        bv[2 * r + 1] = *(const v4i*)(pb + 4);
    }

    for (int kt = 0; kt < KSTEPS; ++kt) {
        // ---- pack current tile regs -> LDS (swizzled) ----
#pragma unroll
        for (int r = 0; r < 4; ++r) {
            int2 pa2, pb2;
            pa2.x = pack4(av[2*r].x,   av[2*r].y,   av[2*r].z,   av[2*r].w);
            pa2.y = pack4(av[2*r+1].x, av[2*r+1].y, av[2*r+1].z, av[2*r+1].w);
            pb2.x = pack4(bv[2*r].x,   bv[2*r].y,   bv[2*r].z,   bv[2*r].w);
            pb2.y = pack4(bv[2*r+1].x, bv[2*r+1].y, bv[2*r+1].z, bv[2*r+1].w);
            *(int2*)(As + wr_off[r]) = pa2;
            *(int2*)(Bs + wr_off[r]) = pb2;
        }

        // ---- prefetch next tile into regs (in flight during MFMA phase) ----
        const int kn = (kt + 1 < KSTEPS) ? (kt + 1) : kt;
        const int koff = kn * TK;
#pragma unroll
        for (int r = 0; r < 4; ++r) {
            const int* pa = Ag + (size_t)r * 32 * K_DIM + koff;
            const int* pb = Bg + (size_t)r * 32 * K_DIM + koff;
            av[2 * r]     = *(const v4i*)(pa);
            av[2 * r + 1] = *(const v4i*)(pa + 4);
            bv[2 * r]     = *(const v4i*)(pb);
            bv[2 * r + 1] = *(const v4i*)(pb + 4);
        }

        __syncthreads();   // ds_writes visible to all waves

        v4i a[4], b[4];
#pragma unroll
        for (int i = 0; i < 4; ++i) a[i] = *(const v4i*)(As + a_off[i]);
#pragma unroll
        for (int j = 0; j < 4; ++j) b[j] = *(const v4i*)(Bs + b_off[j]);

#pragma unroll
        for (int i = 0; i < 4; ++i)
#pragma unroll
            for (int j = 0; j < 4; ++j)
                acc[i][j] = __builtin_amdgcn_mfma_i32_16x16x64_i8(a[i], b[j], acc[i][j], 0, 0, 0);

        __syncthreads();   // LDS reads done before next iteration's writes
    }

    // ---- epilogue: y = alpha*acc + bias ----
    // C/D layout (m89, dtype-independent): col = lane&15, row = quad*4 + reg
    const float alpha = *alphap;
#pragma unroll
    for (int j = 0; j < 4; ++j) {
        const int col = n0 + wn + j * 16 + lrow;
        const float bj = bias[col];
#pragma unroll
        for (int i = 0; i < 4; ++i) {
            const size_t rbase = (size_t)(m0 + wm + i * 16 + quad * 4) * N_DIM + col;
#pragma unroll
            for (int r = 0; r < 4; ++r)
                Y[rbase + (size_t)r * N_DIM] = fmaf(alpha, (float)acc[i][j][r], bj);
        }
    }
}

extern "C" void kernel_launch(void* const* d_in, const int* in_sizes, int n_in,
                              void* d_out, int out_size, void* d_ws, size_t ws_size,
                              hipStream_t stream) {
    const int*   X     = (const int*)d_in[0];     // [4,2048,4096] int8-in-int32
    const int*   Wt    = (const int*)d_in[1];     // [4096,4096]  int8-in-int32
    const float* bias  = (const float*)d_in[2];   // [1,4096] fp32
    const float* alpha = (const float*)d_in[3];   // scalar fp32
    float* Y = (float*)d_out;                     // [4,2048,4096] fp32

    const int M = in_sizes[0] / K_DIM;            // 8192
    dim3 grid(M / TM, N_DIM / TN);                // 64 x 32 = 2048 blocks
    w8a8_gemm<<<grid, dim3(256), 0, stream>>>(X, Wt, bias, alpha, Y);
}

// Round 3
// 424.960 us; speedup vs baseline: 1.5676x; 1.5676x over previous
//
#include <hip/hip_runtime.h>
#include <stdint.h>

typedef int v4i __attribute__((ext_vector_type(4)));

constexpr int K_DIM = 4096;
constexpr int N_DIM = 4096;
constexpr int TM = 128;
constexpr int TN = 128;
constexpr int TK = 64;               // one i8 MFMA K-step per tile
constexpr int KSTEPS = K_DIM / TK;   // 64

// pack low bytes of 4 int32 (each holding one int8 value) into one dword
__device__ __forceinline__ int pack4(int a, int b, int c, int d) {
    unsigned r = (unsigned(a) & 0xFFu)
               | ((unsigned(b) & 0xFFu) << 8)
               | ((unsigned(c) & 0xFFu) << 16)
               | (unsigned(d) << 24);
    return (int)r;
}

// ---------------- pre-pack: int8-in-int32 -> packed int8 ----------------
// Each thread: read 16 int32 (64 B), write 16 int8 (16 B). Memory-bound.
__global__ __launch_bounds__(256) void pack_i32_to_i8(
    const int* __restrict__ src, int8_t* __restrict__ dst, int n16)
{
    int idx = blockIdx.x * blockDim.x + threadIdx.x;
    if (idx >= n16) return;
    const v4i* s = (const v4i*)src + (size_t)idx * 4;
    v4i a = s[0], b = s[1], c = s[2], d = s[3];
    v4i o;
    o.x = pack4(a.x, a.y, a.z, a.w);
    o.y = pack4(b.x, b.y, b.z, b.w);
    o.z = pack4(c.x, c.y, c.z, c.w);
    o.w = pack4(d.x, d.y, d.z, d.w);
    ((v4i*)dst)[idx] = o;
}

// async global->LDS, 16 B per lane. LDS dest = wave-uniform base + lane*16.
__device__ __forceinline__ void gld16(const int8_t* g, int8_t* l) {
    __builtin_amdgcn_global_load_lds(
        (const __attribute__((address_space(1))) char*)g,
        (__attribute__((address_space(3))) char*)l,
        16, 0, 0);
}

// ---------------- main GEMM on packed int8 (m97 structure) ----------------
// C[m][n] = alpha * sum_k X[m][k]*W[n][k] + bias[n]
// Block tile 128x128, 4 waves (2x2 of 64x64), 4x4 of 16x16x64 i8 MFMAs/wave.
// LDS swizzle: 16B chunk-slot s of row r holds global k-chunk s ^ ((r>>1)&3)
// (validated in round 2: same formula both sides, 0 bank conflicts).
__global__ __launch_bounds__(256) void w8a8_gemm_packed(
    const int8_t* __restrict__ X,     // [M][K] int8 (packed)
    const int8_t* __restrict__ Wt,    // [N][K] int8 (packed, row-major = B^T)
    const float*  __restrict__ bias,  // [N]
    const float*  __restrict__ alphap,
    float* __restrict__ Y)            // [M][N] fp32
{
    __shared__ __align__(16) int8_t As[TM * TK];  // 8 KB
    __shared__ __align__(16) int8_t Bs[TN * TK];  // 8 KB

    const int tid  = threadIdx.x;
    const int lane = tid & 63;
    const int wave = tid >> 6;

    const int m0 = blockIdx.x * TM;
    const int n0 = blockIdx.y * TN;

    // ---- staging geometry ----
    // Chunk c0 in [0,256): row = c0>>2, slot = c0&3; issue-1 chunk = c0+256
    // (row+64, same f since 64>>1 = 32 ≡ 0 mod 4). Source k-chunk = slot ^ f(row).
    const int c0   = wave * 64 + lane;
    const int srow = c0 >> 2;
    const int gko  = ((c0 & 3) ^ ((srow >> 1) & 3)) << 4;

    const int8_t* Ag0 = X  + (size_t)(m0 + srow) * K_DIM + gko;
    const int8_t* Bg0 = Wt + (size_t)(n0 + srow) * K_DIM + gko;
    const size_t  half = (size_t)64 * K_DIM;   // rows +64 for issue 1

    int8_t* Al0 = As + wave * 1024;   // issue 0 dest; issue 1 at +4096
    int8_t* Bl0 = Bs + wave * 1024;

    // ---- compute geometry ----
    const int wm   = (wave & 1) << 6;
    const int wn   = (wave >> 1) << 6;
    const int lrow = lane & 15;       // m (A) / n (B) within 16-tile
    const int quad = lane >> 4;       // k-chunk selector

    int a_off[4], b_off[4];
#pragma unroll
    for (int i = 0; i < 4; ++i) {
        const int ra = wm + i * 16 + lrow;
        a_off[i] = ra * 64 + ((quad ^ ((ra >> 1) & 3)) << 4);
        const int rb = wn + i * 16 + lrow;
        b_off[i] = rb * 64 + ((quad ^ ((rb >> 1) & 3)) << 4);
    }

    v4i acc[4][4] = {};

    for (int kt = 0; kt < KSTEPS; ++kt) {
        const int kb = kt * TK;
        gld16(Ag0 + kb,        Al0);
        gld16(Ag0 + half + kb, Al0 + 4096);
        gld16(Bg0 + kb,        Bl0);
        gld16(Bg0 + half + kb, Bl0 + 4096);
        __syncthreads();   // vmcnt(0) drain before barrier -> staging complete

        v4i a[4], b[4];
#pragma unroll
        for (int i = 0; i < 4; ++i) a[i] = *(const v4i*)(As + a_off[i]);
#pragma unroll
        for (int j = 0; j < 4; ++j) b[j] = *(const v4i*)(Bs + b_off[j]);

#pragma unroll
        for (int i = 0; i < 4; ++i)
#pragma unroll
            for (int j = 0; j < 4; ++j)
                acc[i][j] = __builtin_amdgcn_mfma_i32_16x16x64_i8(a[i], b[j], acc[i][j], 0, 0, 0);

        __syncthreads();   // LDS reads done before next iteration's staging
    }

    // ---- epilogue: y = alpha*acc + bias ----
    // C/D layout (m89, dtype-independent): col = lane&15, row = quad*4 + reg
    const float alpha = *alphap;
#pragma unroll
    for (int j = 0; j < 4; ++j) {
        const int col = n0 + wn + j * 16 + lrow;
        const float bj = bias[col];
#pragma unroll
        for (int i = 0; i < 4; ++i) {
            const size_t rbase = (size_t)(m0 + wm + i * 16 + quad * 4) * N_DIM + col;
#pragma unroll
            for (int r = 0; r < 4; ++r)
                Y[rbase + (size_t)r * N_DIM] = fmaf(alpha, (float)acc[i][j][r], bj);
        }
    }
}

// ---------------- fallback (round-2 kernel, known-good, no ws needed) ------
__global__ __launch_bounds__(256, 2) void w8a8_gemm_fb(
    const int*   __restrict__ X,
    const int*   __restrict__ Wt,
    const float* __restrict__ bias,
    const float* __restrict__ alphap,
    float* __restrict__ Y)
{
    __shared__ __align__(16) int8_t As[TM * TK];
    __shared__ __align__(16) int8_t Bs[TN * TK];

    const int tid  = threadIdx.x;
    const int lane = tid & 63;
    const int wave = tid >> 6;
    const int m0 = blockIdx.x * TM;
    const int n0 = blockIdx.y * TN;

    const int srow = tid >> 3;
    const int sk   = (tid & 7) * 8;
    const int* Ag = X  + (size_t)(m0 + srow) * K_DIM + sk;
    const int* Bg = Wt + (size_t)(n0 + srow) * K_DIM + sk;

    int wr_off[4];
#pragma unroll
    for (int r = 0; r < 4; ++r) {
        const int row = r * 32 + (tid >> 3);
        const int dw  = (tid & 7) * 2;
        const int sw  = row * 16 + (((dw >> 2) ^ ((row >> 1) & 3)) << 2) + (dw & 3);
        wr_off[r] = sw * 4;
    }

    const int wm   = (wave & 1) << 6;
    const int wn   = (wave >> 1) << 6;
    const int lrow = lane & 15;
    const int quad = lane >> 4;

    int a_off[4], b_off[4];
#pragma unroll
    for (int i = 0; i < 4; ++i) {
        const int ra = wm + i * 16 + lrow;
        a_off[i] = ra * 64 + ((quad ^ ((ra >> 1) & 3)) << 4);
        const int rb = wn + i * 16 + lrow;
        b_off[i] = rb * 64 + ((quad ^ ((rb >> 1) & 3)) << 4);
    }

    v4i acc[4][4] = {};
    v4i av[8], bv[8];
#pragma unroll
    for (int r = 0; r < 4; ++r) {
        const int* pa = Ag + (size_t)r * 32 * K_DIM;
        const int* pb = Bg + (size_t)r * 32 * K_DIM;
        av[2 * r] = *(const v4i*)(pa);  av[2 * r + 1] = *(const v4i*)(pa + 4);
        bv[2 * r] = *(const v4i*)(pb);  bv[2 * r + 1] = *(const v4i*)(pb + 4);
    }

    for (int kt = 0; kt < KSTEPS; ++kt) {
#pragma unroll
        for (int r = 0; r < 4; ++r) {
            int2 pa2, pb2;
            pa2.x = pack4(av[2*r].x,   av[2*r].y,   av[2*r].z,   av[2*r].w);
            pa2.y = pack4(av[2*r+1].x, av[2*r+1].y, av[2*r+1].z, av[2*r+1].w);
            pb2.x = pack4(bv[2*r].x,   bv[2*r].y,   bv[2*r].z,   bv[2*r].w);
            pb2.y = pack4(bv[2*r+1].x, bv[2*r+1].y, bv[2*r+1].z, bv[2*r+1].w);
            *(int2*)(As + wr_off[r]) = pa2;
            *(int2*)(Bs + wr_off[r]) = pb2;
        }
        const int kn = (kt + 1 < KSTEPS) ? (kt + 1) : kt;
        const int koff = kn * TK;
#pragma unroll
        for (int r = 0; r < 4; ++r) {
            const int* pa = Ag + (size_t)r * 32 * K_DIM + koff;
            const int* pb = Bg + (size_t)r * 32 * K_DIM + koff;
            av[2 * r] = *(const v4i*)(pa);  av[2 * r + 1] = *(const v4i*)(pa + 4);
            bv[2 * r] = *(const v4i*)(pb);  bv[2 * r + 1] = *(const v4i*)(pb + 4);
        }
        __syncthreads();
        v4i a[4], b[4];
#pragma unroll
        for (int i = 0; i < 4; ++i) a[i] = *(const v4i*)(As + a_off[i]);
#pragma unroll
        for (int j = 0; j < 4; ++j) b[j] = *(const v4i*)(Bs + b_off[j]);
#pragma unroll
        for (int i = 0; i < 4; ++i)
#pragma unroll
            for (int j = 0; j < 4; ++j)
                acc[i][j] = __builtin_amdgcn_mfma_i32_16x16x64_i8(a[i], b[j], acc[i][j], 0, 0, 0);
        __syncthreads();
    }

    const float alpha = *alphap;
#pragma unroll
    for (int j = 0; j < 4; ++j) {
        const int col = n0 + wn + j * 16 + lrow;
        const float bj = bias[col];
#pragma unroll
        for (int i = 0; i < 4; ++i) {
            const size_t rbase = (size_t)(m0 + wm + i * 16 + quad * 4) * N_DIM + col;
#pragma unroll
            for (int r = 0; r < 4; ++r)
                Y[rbase + (size_t)r * N_DIM] = fmaf(alpha, (float)acc[i][j][r], bj);
        }
    }
}

extern "C" void kernel_launch(void* const* d_in, const int* in_sizes, int n_in,
                              void* d_out, int out_size, void* d_ws, size_t ws_size,
                              hipStream_t stream) {
    const int*   X32   = (const int*)d_in[0];     // [4,2048,4096] int8-in-int32
    const int*   W32   = (const int*)d_in[1];     // [4096,4096]  int8-in-int32
    const float* bias  = (const float*)d_in[2];   // [1,4096] fp32
    const float* alpha = (const float*)d_in[3];   // scalar fp32
    float* Y = (float*)d_out;                     // [4,2048,4096] fp32

    const int nX = in_sizes[0];                   // 33554432
    const int nW = in_sizes[1];                   // 16777216
    const int M  = nX / K_DIM;                    // 8192
    dim3 grid(M / TM, N_DIM / TN);                // 64 x 32 = 2048 blocks

    if (ws_size >= (size_t)nX + (size_t)nW) {
        int8_t* Xp = (int8_t*)d_ws;
        int8_t* Wp = Xp + nX;
        const int nX16 = nX / 16, nW16 = nW / 16;
        pack_i32_to_i8<<<(nX16 + 255) / 256, 256, 0, stream>>>(X32, Xp, nX16);
        pack_i32_to_i8<<<(nW16 + 255) / 256, 256, 0, stream>>>(W32, Wp, nW16);
        w8a8_gemm_packed<<<grid, dim3(256), 0, stream>>>(Xp, Wp, bias, alpha, Y);
    } else {
        w8a8_gemm_fb<<<grid, dim3(256), 0, stream>>>(X32, W32, bias, alpha, Y);
    }
}

// Round 4
// 420.080 us; speedup vs baseline: 1.5858x; 1.0116x over previous
//
#include <hip/hip_runtime.h>
#include <stdint.h>

typedef int v4i __attribute__((ext_vector_type(4)));

constexpr int K_DIM = 4096;
constexpr int N_DIM = 4096;
constexpr int TM = 128;
constexpr int TN = 128;
constexpr int TK = 128;              // two i8 MFMA K-steps per barrier pair
constexpr int KSTEPS = K_DIM / TK;   // 32

// pack low bytes of 4 int32 (each holding one int8 value) into one dword
__device__ __forceinline__ int pack4(int a, int b, int c, int d) {
    unsigned r = (unsigned(a) & 0xFFu)
               | ((unsigned(b) & 0xFFu) << 8)
               | ((unsigned(c) & 0xFFu) << 16)
               | (unsigned(d) << 24);
    return (int)r;
}

// ---------------- pre-pack: int8-in-int32 -> packed int8 (fused X+W) -------
// One output dword per thread: read v4i (16 B/lane, 1 KB contiguous per wave),
// write 1 dword (256 B contiguous per wave). Fully coalesced both sides.
__global__ __launch_bounds__(256) void pack_both(
    const int* __restrict__ s1, int* __restrict__ d1, int n1,   // dwords out
    const int* __restrict__ s2, int* __restrict__ d2, int n2)
{
    int idx = blockIdx.x * blockDim.x + threadIdx.x;
    const int* s;
    int* d;
    if (idx < n1) { s = s1; d = d1; }
    else if (idx < n1 + n2) { s = s2; d = d2; idx -= n1; }
    else return;
    v4i v = ((const v4i*)s)[idx];
    d[idx] = pack4(v.x, v.y, v.z, v.w);
}

// async global->LDS, 16 B per lane. LDS dest = wave-uniform base + lane*16.
__device__ __forceinline__ void gld16(const int8_t* g, int8_t* l) {
    __builtin_amdgcn_global_load_lds(
        (const __attribute__((address_space(1))) char*)g,
        (__attribute__((address_space(3))) char*)l,
        16, 0, 0);
}

// ---------------- main GEMM on packed int8, TK=128 ----------------
// C[m][n] = alpha * sum_k X[m][k]*W[n][k] + bias[n]
// Block 128x128, 4 waves (2x2 of 64x64), 2 k-halves x 4x4 16x16x64 MFMAs/wave
// per barrier pair. LDS row = 128 B = 8 chunks of 16 B; chunk-slot s of row r
// holds global k-chunk s ^ f(r), f(r) = (r>>1)&7  -> conflict-free b128 reads.
// slot(kk=1) = slot(kk=0) ^ 4  =>  fragment addr just XORs 64.
__global__ __launch_bounds__(256) void w8a8_gemm_packed(
    const int8_t* __restrict__ X,     // [M][K] int8 (packed)
    const int8_t* __restrict__ Wt,    // [N][K] int8 (packed, row-major = B^T)
    const float*  __restrict__ bias,  // [N]
    const float*  __restrict__ alphap,
    float* __restrict__ Y)            // [M][N] fp32
{
    __shared__ __align__(16) int8_t As[TM * TK];  // 16 KB
    __shared__ __align__(16) int8_t Bs[TN * TK];  // 16 KB

    const int tid  = threadIdx.x;
    const int lane = tid & 63;
    const int wave = tid >> 6;

    const int m0 = blockIdx.x * TM;
    const int n0 = blockIdx.y * TN;

    // ---- staging geometry ----
    // 1024 chunks per tile. Wave w, issue i in [0,4): chunk c = (w*4+i)*64+lane.
    // row = c>>3, slot = c&7, source k-chunk = slot ^ f(row).
    const int8_t* Aga[4];
    const int8_t* Bga[4];
    int lds_off[4];
#pragma unroll
    for (int i = 0; i < 4; ++i) {
        const int c    = (wave * 4 + i) * 64 + lane;
        const int row  = c >> 3;
        const int gko  = ((c & 7) ^ ((row >> 1) & 7)) << 4;
        Aga[i] = X  + (size_t)(m0 + row) * K_DIM + gko;
        Bga[i] = Wt + (size_t)(n0 + row) * K_DIM + gko;
        lds_off[i] = c << 4;   // c*16
    }

    // ---- compute geometry ----
    const int wm   = (wave & 1) << 6;
    const int wn   = (wave >> 1) << 6;
    const int lrow = lane & 15;       // m (A) / n (B) within 16-tile
    const int quad = lane >> 4;       // k-chunk selector

    int a_off[4], b_off[4];           // kk=0 offsets; kk=1 = ^64
#pragma unroll
    for (int i = 0; i < 4; ++i) {
        const int ra = wm + i * 16 + lrow;
        a_off[i] = ra * TK + ((quad ^ ((ra >> 1) & 7)) << 4);
        const int rb = wn + i * 16 + lrow;
        b_off[i] = rb * TK + ((quad ^ ((rb >> 1) & 7)) << 4);
    }

    v4i acc[4][4] = {};

    for (int kt = 0; kt < KSTEPS; ++kt) {
        const int kb = kt * TK;
#pragma unroll
        for (int i = 0; i < 4; ++i) {
            gld16(Aga[i] + kb, As + lds_off[i]);
            gld16(Bga[i] + kb, Bs + lds_off[i]);
        }
        __syncthreads();   // vmcnt(0) drain -> 32 KB staged

#pragma unroll
        for (int kk = 0; kk < 2; ++kk) {
            const int kx = kk << 6;   // XOR 64 selects k-half (slot^4)
            v4i a[4], b[4];
#pragma unroll
            for (int i = 0; i < 4; ++i) a[i] = *(const v4i*)(As + (a_off[i] ^ kx));
#pragma unroll
            for (int j = 0; j < 4; ++j) b[j] = *(const v4i*)(Bs + (b_off[j] ^ kx));
#pragma unroll
            for (int i = 0; i < 4; ++i)
#pragma unroll
                for (int j = 0; j < 4; ++j)
                    acc[i][j] = __builtin_amdgcn_mfma_i32_16x16x64_i8(a[i], b[j], acc[i][j], 0, 0, 0);
        }

        __syncthreads();   // LDS reads done before next iteration's staging
    }

    // ---- epilogue: y = alpha*acc + bias ----
    // C/D layout (m89, dtype-independent): col = lane&15, row = quad*4 + reg
    const float alpha = *alphap;
#pragma unroll
    for (int j = 0; j < 4; ++j) {
        const int col = n0 + wn + j * 16 + lrow;
        const float bj = bias[col];
#pragma unroll
        for (int i = 0; i < 4; ++i) {
            const size_t rbase = (size_t)(m0 + wm + i * 16 + quad * 4) * N_DIM + col;
#pragma unroll
            for (int r = 0; r < 4; ++r)
                Y[rbase + (size_t)r * N_DIM] = fmaf(alpha, (float)acc[i][j][r], bj);
        }
    }
}

// ---------------- fallback (round-2 kernel, known-good, no ws needed) ------
__global__ __launch_bounds__(256, 2) void w8a8_gemm_fb(
    const int*   __restrict__ X,
    const int*   __restrict__ Wt,
    const float* __restrict__ bias,
    const float* __restrict__ alphap,
    float* __restrict__ Y)
{
    __shared__ __align__(16) int8_t As[TM * 64];
    __shared__ __align__(16) int8_t Bs[TN * 64];

    const int tid  = threadIdx.x;
    const int lane = tid & 63;
    const int wave = tid >> 6;
    const int m0 = blockIdx.x * TM;
    const int n0 = blockIdx.y * TN;

    const int srow = tid >> 3;
    const int sk   = (tid & 7) * 8;
    const int* Ag = X  + (size_t)(m0 + srow) * K_DIM + sk;
    const int* Bg = Wt + (size_t)(n0 + srow) * K_DIM + sk;

    int wr_off[4];
#pragma unroll
    for (int r = 0; r < 4; ++r) {
        const int row = r * 32 + (tid >> 3);
        const int dw  = (tid & 7) * 2;
        const int sw  = row * 16 + (((dw >> 2) ^ ((row >> 1) & 3)) << 2) + (dw & 3);
        wr_off[r] = sw * 4;
    }

    const int wm   = (wave & 1) << 6;
    const int wn   = (wave >> 1) << 6;
    const int lrow = lane & 15;
    const int quad = lane >> 4;

    int a_off[4], b_off[4];
#pragma unroll
    for (int i = 0; i < 4; ++i) {
        const int ra = wm + i * 16 + lrow;
        a_off[i] = ra * 64 + ((quad ^ ((ra >> 1) & 3)) << 4);
        const int rb = wn + i * 16 + lrow;
        b_off[i] = rb * 64 + ((quad ^ ((rb >> 1) & 3)) << 4);
    }

    v4i acc[4][4] = {};
    v4i av[8], bv[8];
#pragma unroll
    for (int r = 0; r < 4; ++r) {
        const int* pa = Ag + (size_t)r * 32 * K_DIM;
        const int* pb = Bg + (size_t)r * 32 * K_DIM;
        av[2 * r] = *(const v4i*)(pa);  av[2 * r + 1] = *(const v4i*)(pa + 4);
        bv[2 * r] = *(const v4i*)(pb);  bv[2 * r + 1] = *(const v4i*)(pb + 4);
    }

    for (int kt = 0; kt < 64; ++kt) {
#pragma unroll
        for (int r = 0; r < 4; ++r) {
            int2 pa2, pb2;
            pa2.x = pack4(av[2*r].x,   av[2*r].y,   av[2*r].z,   av[2*r].w);
            pa2.y = pack4(av[2*r+1].x, av[2*r+1].y, av[2*r+1].z, av[2*r+1].w);
            pb2.x = pack4(bv[2*r].x,   bv[2*r].y,   bv[2*r].z,   bv[2*r].w);
            pb2.y = pack4(bv[2*r+1].x, bv[2*r+1].y, bv[2*r+1].z, bv[2*r+1].w);
            *(int2*)(As + wr_off[r]) = pa2;
            *(int2*)(Bs + wr_off[r]) = pb2;
        }
        const int kn = (kt + 1 < 64) ? (kt + 1) : kt;
        const int koff = kn * 64;
#pragma unroll
        for (int r = 0; r < 4; ++r) {
            const int* pa = Ag + (size_t)r * 32 * K_DIM + koff;
            const int* pb = Bg + (size_t)r * 32 * K_DIM + koff;
            av[2 * r] = *(const v4i*)(pa);  av[2 * r + 1] = *(const v4i*)(pa + 4);
            bv[2 * r] = *(const v4i*)(pb);  bv[2 * r + 1] = *(const v4i*)(pb + 4);
        }
        __syncthreads();
        v4i a[4], b[4];
#pragma unroll
        for (int i = 0; i < 4; ++i) a[i] = *(const v4i*)(As + a_off[i]);
#pragma unroll
        for (int j = 0; j < 4; ++j) b[j] = *(const v4i*)(Bs + b_off[j]);
#pragma unroll
        for (int i = 0; i < 4; ++i)
#pragma unroll
            for (int j = 0; j < 4; ++j)
                acc[i][j] = __builtin_amdgcn_mfma_i32_16x16x64_i8(a[i], b[j], acc[i][j], 0, 0, 0);
        __syncthreads();
    }

    const float alpha = *alphap;
#pragma unroll
    for (int j = 0; j < 4; ++j) {
        const int col = n0 + wn + j * 16 + lrow;
        const float bj = bias[col];
#pragma unroll
        for (int i = 0; i < 4; ++i) {
            const size_t rbase = (size_t)(m0 + wm + i * 16 + quad * 4) * N_DIM + col;
#pragma unroll
            for (int r = 0; r < 4; ++r)
                Y[rbase + (size_t)r * N_DIM] = fmaf(alpha, (float)acc[i][j][r], bj);
        }
    }
}

extern "C" void kernel_launch(void* const* d_in, const int* in_sizes, int n_in,
                              void* d_out, int out_size, void* d_ws, size_t ws_size,
                              hipStream_t stream) {
    const int*   X32   = (const int*)d_in[0];     // [4,2048,4096] int8-in-int32
    const int*   W32   = (const int*)d_in[1];     // [4096,4096]  int8-in-int32
    const float* bias  = (const float*)d_in[2];   // [1,4096] fp32
    const float* alpha = (const float*)d_in[3];   // scalar fp32
    float* Y = (float*)d_out;                     // [4,2048,4096] fp32

    const int nX = in_sizes[0];                   // 33554432
    const int nW = in_sizes[1];                   // 16777216
    const int M  = nX / K_DIM;                    // 8192
    dim3 grid(M / TM, N_DIM / TN);                // 64 x 32 = 2048 blocks

    if (ws_size >= (size_t)nX + (size_t)nW) {
        int8_t* Xp = (int8_t*)d_ws;
        int8_t* Wp = Xp + nX;
        const int n1 = nX / 4, n2 = nW / 4;       // output dwords
        const int nthreads = n1 + n2;
        pack_both<<<(nthreads + 255) / 256, 256, 0, stream>>>(
            X32, (int*)Xp, n1, W32, (int*)Wp, n2);
        w8a8_gemm_packed<<<grid, dim3(256), 0, stream>>>(Xp, Wp, bias, alpha, Y);
    } else {
        w8a8_gemm_fb<<<grid, dim3(256), 0, stream>>>(X32, W32, bias, alpha, Y);
    }
}